// Round 6
// baseline (704.524 us; speedup 1.0000x reference)
//
#include <hip/hip_runtime.h>
#include <cfloat>

#define N_ROWS 16384
#define DDIM   768
#define KCOLS  10000
#define KPAD   10240   // 40 * 256

typedef __attribute__((ext_vector_type(4))) float f32x4;
typedef __attribute__((ext_vector_type(8))) short s16x8;
typedef unsigned long long u64;
typedef unsigned int u32;

__device__ __forceinline__ u32 fsort(float f) {
  u32 u = __float_as_uint(f);
  return (u & 0x80000000u) ? ~u : (u | 0x80000000u);
}
__device__ __forceinline__ float funsort(u32 u) {
  u32 b = (u & 0x80000000u) ? (u ^ 0x80000000u) : ~u;
  return __uint_as_float(b);
}
__device__ __forceinline__ unsigned short f2bf(float f) {  // RNE
  u32 b = __float_as_uint(f);
  return (unsigned short)((b + 0x7fffu + ((b >> 16) & 1u)) >> 16);
}
__device__ __forceinline__ float bf2f(unsigned short s) {
  return __uint_as_float(((u32)s) << 16);
}

// ============================ pre-passes ============================

// X [N][768] f32 -> Xb [N][768] bf16, chunk-swizzled: store(d-chunk c) = c ^ (row&7)
// Also initializes best[] (folded launch).
__global__ void convx_kernel(const float* __restrict__ X, unsigned short* __restrict__ Xb,
                             u64* __restrict__ best) {
  int i = blockIdx.x * 256 + threadIdx.x;   // output uint4 (8-elem chunk) index
  if (i < N_ROWS) best[i] = ~0ULL;
  int row = i / 96;
  int pc  = i % 96;                          // physical chunk within row
  int lc  = pc ^ (row & 7);                  // logical chunk (xor bits 0-2 only)
  const float4* p = (const float4*)(X + (size_t)row * DDIM + lc * 8);
  float4 a = p[0], b = p[1];
  union { unsigned short s[8]; uint4 v; } o;
  o.s[0] = f2bf(a.x); o.s[1] = f2bf(a.y); o.s[2] = f2bf(a.z); o.s[3] = f2bf(a.w);
  o.s[4] = f2bf(b.x); o.s[5] = f2bf(b.y); o.s[6] = f2bf(b.z); o.s[7] = f2bf(b.w);
  *((uint4*)Xb + i) = o.v;
}

// C [768][10000] f32 -> Cb [10240][768] bf16 (swizzled) + Ct [10240][768] f32 (linear)
__global__ void transc_kernel(const float* __restrict__ C, unsigned short* __restrict__ Cb,
                              float* __restrict__ Ct) {
  __shared__ float tile[32][33];
  int t = threadIdx.x, tx = t & 31, ty = t >> 5;
  int kk = blockIdx.x * 32, dd = blockIdx.y * 32;
#pragma unroll
  for (int j = 0; j < 4; ++j) {
    int d = dd + ty + j * 8, k = kk + tx;
    tile[ty + j * 8][tx] = (k < KCOLS) ? C[(size_t)d * KCOLS + k] : 0.f;
  }
  __syncthreads();
#pragma unroll
  for (int j = 0; j < 4; ++j) {
    int k = kk + ty + j * 8, d = dd + tx;
    float v = tile[tx][ty + j * 8];
    Cb[(size_t)k * DDIM + (d ^ ((k & 7) << 3))] = f2bf(v);
    if (Ct) Ct[(size_t)k * DDIM + d] = v;
  }
}

// cnorm, 2D-parallel, deterministic fixed-order reduction. grid = KPAD/64.
__global__ __launch_bounds__(256) void cnorm2_kernel(const float* __restrict__ C,
                                                     float* __restrict__ cn) {
  __shared__ float part[4][64];
  const int tx = threadIdx.x & 63, ty = threadIdx.x >> 6;
  const int k = blockIdx.x * 64 + tx;
  float s = 0.f;
  if (k < KCOLS) {
    const float* p = C + (size_t)(ty * 192) * KCOLS + k;
    for (int d = 0; d < 192; ++d) {
      float v = p[(size_t)d * KCOLS];
      s = fmaf(v, v, s);
    }
  }
  part[ty][tx] = s;
  __syncthreads();
  if (ty == 0)
    cn[k] = (k < KCOLS) ? ((part[0][tx] + part[1][tx]) + (part[2][tx] + part[3][tx]))
                        : FLT_MAX;
}

// Seed amin[row]: approx scores of 64 sampled centroids (lane = candidate).
__global__ __launch_bounds__(256) void seed_kernel(
    const float* __restrict__ X32, const unsigned short* __restrict__ Cb,
    const float* __restrict__ cn, u32* __restrict__ amin) {
  __shared__ float xs[4][DDIM];
  const int wave = threadIdx.x >> 6, lane = threadIdx.x & 63;
  const int row = blockIdx.x * 4 + wave;
  const float4* xr = (const float4*)(X32 + (size_t)row * DDIM);
#pragma unroll
  for (int p0 = 0; p0 < 3; ++p0)
    ((float4*)xs[wave])[lane + p0 * 64] = xr[lane + p0 * 64];
  const int k = lane * 158;                 // 0..9954
  const int ksw = k & 7;
  const uint4* crow = (const uint4*)(Cb + (size_t)k * DDIM);
  float dot = 0.f;
  for (int p = 0; p < 96; ++p) {
    union { uint4 v; unsigned short s[8]; } cv;
    cv.v = crow[p];
    const float* xp = xs[wave] + ((p ^ ksw) * 8);
#pragma unroll
    for (int j = 0; j < 8; ++j) dot = fmaf(xp[j], bf2f(cv.s[j]), dot);
  }
  float score = fmaf(-2.f, dot, cn[k]);
#pragma unroll
  for (int s = 1; s < 64; s <<= 1) score = fminf(score, __shfl_xor(score, s));
  if (lane == 0) amin[row] = fsort(score);
}

// ============================ fused GEMM + argmin (ring pipeline) ============================

#define GLOAD_LDS16(gp, lp)                                                     \
  __builtin_amdgcn_global_load_lds((const __attribute__((address_space(1))) void*)(gp), \
                                   (__attribute__((address_space(3))) void*)(lp), 16, 0, 0)

// Tile: 128 rows (X) x 256 cols (centroids), BK=64. 8 waves (2M x 4N), per-wave 64x64.
// LDS: 3-deep ring of K-tiles (A 16KB + B 32KB = 48KB each) = 144 KiB.
// Window w: compute tile w from ring[w%3]; stage tile w+2 into ring[(w+2)%3]
// (consumed at window w-1). Boundary: vmcnt(6) keeps next tile's 6 loads in flight.
__global__ __launch_bounds__(512, 2) void assign_mfma8(
    const unsigned short* __restrict__ Xb, const unsigned short* __restrict__ Cb,
    const float* __restrict__ X32, const float* __restrict__ C32,
    const float* __restrict__ Ct, const float* __restrict__ cn,
    u32* __restrict__ amin, u64* __restrict__ best) {
  __shared__ __align__(16) unsigned short ring[3][24576];  // [tile]: A[0..8192) B[8192..24576)

  const int t = threadIdx.x;
  const int lane = t & 63, wave = t >> 6;
  const int wr = wave >> 2, wc = wave & 3;    // 2M x 4N wave grid
  const int bid = blockIdx.x;
  const int wg = (bid & 7) * 640 + (bid >> 3);   // bijective XCD swizzle (5120 % 8 == 0)
  const int n0 = (wg % 128) * 128;
  const int k0 = (wg / 128) * 256;
  const int lr = lane & 15, lg = lane >> 4;
  const int xr = lr & 7;                       // read-side swizzle key
  const int srow = lane >> 3, schunk = lane & 7;

  f32x4 acc[4][4];
  f32x4 z = {0.f, 0.f, 0.f, 0.f};
#pragma unroll
  for (int m = 0; m < 4; ++m)
#pragma unroll
    for (int n = 0; n < 4; ++n) acc[m][n] = z;

  // per-lane staging source pointers
  const unsigned short* gA = Xb + (size_t)(n0 + wave * 8 + srow) * DDIM + schunk * 8;
  const unsigned short* gB = Cb + (size_t)(k0 + wave * 8 + srow) * DDIM + schunk * 8;
  // wave-uniform LDS dest offsets (shorts)
  const int ldA = wave * 512;            // (wave*8 rows) * 64 shorts/row
  const int ldB = 8192 + wave * 512;

  // -------- prologue: stage tiles 0 and 1 (6 loads each, tile-0 loads oldest) --------
#pragma unroll
  for (int tt = 0; tt < 2; ++tt) {
#pragma unroll
    for (int j = 0; j < 2; ++j)
      GLOAD_LDS16(gA + tt * 64 + (size_t)j * 64 * DDIM, &ring[tt][ldA + j * 4096]);
#pragma unroll
    for (int j = 0; j < 4; ++j)
      GLOAD_LDS16(gB + tt * 64 + (size_t)j * 64 * DDIM, &ring[tt][ldB + j * 4096]);
  }
  const unsigned short* gA2 = gA + 128;   // staging pointer, 2 tiles ahead
  const unsigned short* gB2 = gB + 128;

  int cur = 0, nxt = 2;
  for (int w = 0; w < 12; ++w) {
    // -------- boundary: tile w must be resident; keep tile w+1's 6 loads in flight --------
    __builtin_amdgcn_sched_barrier(0);
    if (w < 11) asm volatile("s_waitcnt vmcnt(6)" ::: "memory");
    else        asm volatile("s_waitcnt vmcnt(0)" ::: "memory");
    __builtin_amdgcn_s_barrier();

    const unsigned short* A = ring[cur];
    const unsigned short* B = ring[cur] + 8192;
    const bool stage = (w < 10);

    // -------- phase 0: issue first half of tile w+2, compute dk=0 --------
    if (stage) {
#pragma unroll
      for (int j = 0; j < 2; ++j)
        GLOAD_LDS16(gA2 + (size_t)j * 64 * DDIM, &ring[nxt][ldA + j * 4096]);
      GLOAD_LDS16(gB2, &ring[nxt][ldB]);
    }
    {
      s16x8 af[4], bf_[4];
      const int c = lg ^ xr;
#pragma unroll
      for (int m = 0; m < 4; ++m)
        af[m] = *(const s16x8*)(A + (wr * 64 + m * 16 + lr) * 64 + c * 8);
#pragma unroll
      for (int n = 0; n < 4; ++n)
        bf_[n] = *(const s16x8*)(B + (wc * 64 + n * 16 + lr) * 64 + c * 8);
      __builtin_amdgcn_s_setprio(1);
#pragma unroll
      for (int m = 0; m < 4; ++m)
#pragma unroll
        for (int n = 0; n < 4; ++n)
          acc[m][n] = __builtin_amdgcn_mfma_f32_16x16x32_bf16(af[m], bf_[n], acc[m][n], 0, 0, 0);
      __builtin_amdgcn_s_setprio(0);
    }
    // -------- phase 1: issue rest of tile w+2, compute dk=1 --------
    if (stage) {
#pragma unroll
      for (int j = 1; j < 4; ++j)
        GLOAD_LDS16(gB2 + (size_t)j * 64 * DDIM, &ring[nxt][ldB + j * 4096]);
    }
    {
      s16x8 af[4], bf_[4];
      const int c = (4 + lg) ^ xr;
#pragma unroll
      for (int m = 0; m < 4; ++m)
        af[m] = *(const s16x8*)(A + (wr * 64 + m * 16 + lr) * 64 + c * 8);
#pragma unroll
      for (int n = 0; n < 4; ++n)
        bf_[n] = *(const s16x8*)(B + (wc * 64 + n * 16 + lr) * 64 + c * 8);
      __builtin_amdgcn_s_setprio(1);
#pragma unroll
      for (int m = 0; m < 4; ++m)
#pragma unroll
        for (int n = 0; n < 4; ++n)
          acc[m][n] = __builtin_amdgcn_mfma_f32_16x16x32_bf16(af[m], bf_[n], acc[m][n], 0, 0, 0);
      __builtin_amdgcn_s_setprio(0);
    }

    gA2 += 64; gB2 += 64;
    cur = (cur == 2) ? 0 : cur + 1;
    nxt = (nxt == 2) ? 0 : nxt + 1;
  }

  // ---------------- epilogue: approx min + exact rescore ----------------
  float cnv[4];
#pragma unroll
  for (int n = 0; n < 4; ++n) cnv[n] = cn[k0 + wc * 64 + n * 16 + lr];

#pragma unroll
  for (int m = 0; m < 4; ++m) {
    float sc[4][4];  // [n][e]
#pragma unroll
    for (int n = 0; n < 4; ++n)
#pragma unroll
      for (int e = 0; e < 4; ++e) sc[n][e] = fmaf(-2.f, acc[m][n][e], cnv[n]);

    float th[4];
#pragma unroll
    for (int e = 0; e < 4; ++e) {
      float v = fminf(fminf(sc[0][e], sc[1][e]), fminf(sc[2][e], sc[3][e]));
      u32 key = fsort(v);
#pragma unroll
      for (int s = 1; s < 16; s <<= 1) {
        u32 o = __shfl_xor(key, s);
        key = key < o ? key : o;
      }
      int row = n0 + wr * 64 + m * 16 + lg * 4 + e;
      u32 mr = key;
      if (lr == 0) {
        u32 old = atomicMin(&amin[row], key);
        mr = old < key ? old : key;
      }
      mr = __shfl(mr, lane & 48);
      th[e] = funsort(mr) + 1.5f;   // margin ~ 7 sigma of bf16-approx error diff
    }

#pragma unroll
    for (int n = 0; n < 4; ++n) {
#pragma unroll
      for (int e = 0; e < 4; ++e) {
        int kq = k0 + wc * 64 + n * 16 + lr;
        bool cand = (kq < KCOLS) && (sc[n][e] <= th[e]);
        u64 mask = __ballot(cand);
        while (mask) {
          int src = (int)__builtin_ctzll(mask);
          mask &= mask - 1;
          int srowg = n0 + wr * 64 + m * 16 + ((src >> 4) & 3) * 4 + e;
          int skg = k0 + wc * 64 + n * 16 + (src & 15);
          // exact fp32 dot, 64-lane parallel
          float part = 0.f;
          const float* xp = X32 + (size_t)srowg * DDIM + lane;
          if (Ct) {
            const float* cp = Ct + (size_t)skg * DDIM + lane;   // coalesced
#pragma unroll
            for (int i = 0; i < 12; ++i)
              part = fmaf(xp[i * 64], cp[i * 64], part);
          } else {
            const float* cp = C32 + (size_t)lane * KCOLS + skg; // scattered fallback
#pragma unroll
            for (int i = 0; i < 12; ++i)
              part = fmaf(xp[i * 64], cp[(size_t)i * 64 * KCOLS], part);
          }
#pragma unroll
          for (int s = 1; s < 64; s <<= 1) part += __shfl_xor(part, s);
          if (lane == 0) {
            float ex = fmaf(-2.f, part, cn[skg]);
            atomicMin(&best[srowg], ((u64)fsort(ex) << 32) | (u32)skg);
          }
        }
      }
    }
  }
}

// ============================ fp32 fallback path ============================

__global__ void cnorm_kernel(const float* __restrict__ C, float* __restrict__ cnorm,
                             int D, int K) {
  int k = blockIdx.x * blockDim.x + threadIdx.x;
  if (k >= K) return;
  float s = 0.f;
  for (int d = 0; d < D; ++d) {
    float v = C[(size_t)d * K + k];
    s = fmaf(v, v, s);
  }
  cnorm[k] = s;
}

__global__ void init_kernel(u64* best, int N) {
  int n = blockIdx.x * blockDim.x + threadIdx.x;
  if (n < N) best[n] = ~0ULL;
}

__global__ __launch_bounds__(256) void assign_kernel(
    const float* __restrict__ X, const float* __restrict__ C,
    const float* __restrict__ cnorm, u64* __restrict__ best,
    int N, int D, int K) {
  __shared__ float Xs[16][128];
  __shared__ float Cs[16][64];
  const int t = threadIdx.x;
  const int tx = t & 15, ty = t >> 4;
  const int k0 = blockIdx.x * 64;
  const int n0 = blockIdx.y * 128;
  float acc[8][4];
#pragma unroll
  for (int i = 0; i < 8; ++i)
#pragma unroll
    for (int j = 0; j < 4; ++j) acc[i][j] = 0.f;
  for (int d0 = 0; d0 < D; d0 += 16) {
#pragma unroll
    for (int v = 0; v < 2; ++v) {
      int f4 = t + v * 256;
      int row = f4 >> 2;
      int dc = (f4 & 3) * 4;
      const float4 xv = *(const float4*)&X[(size_t)(n0 + row) * D + d0 + dc];
      Xs[dc + 0][row] = xv.x; Xs[dc + 1][row] = xv.y;
      Xs[dc + 2][row] = xv.z; Xs[dc + 3][row] = xv.w;
    }
    {
      int d = t >> 4, kc = (t & 15) * 4, k = k0 + kc;
      float4 cv;
      if (k + 3 < K) cv = *(const float4*)&C[(size_t)(d0 + d) * K + k];
      else {
        cv.x = (k + 0 < K) ? C[(size_t)(d0 + d) * K + k + 0] : 0.f;
        cv.y = (k + 1 < K) ? C[(size_t)(d0 + d) * K + k + 1] : 0.f;
        cv.z = (k + 2 < K) ? C[(size_t)(d0 + d) * K + k + 2] : 0.f;
        cv.w = (k + 3 < K) ? C[(size_t)(d0 + d) * K + k + 3] : 0.f;
      }
      *(float4*)&Cs[d][kc] = cv;
    }
    __syncthreads();
#pragma unroll
    for (int d = 0; d < 16; ++d) {
      float4 a0 = *(const float4*)&Xs[d][ty * 8];
      float4 a1 = *(const float4*)&Xs[d][ty * 8 + 4];
      float4 b = *(const float4*)&Cs[d][tx * 4];
      float av[8] = {a0.x, a0.y, a0.z, a0.w, a1.x, a1.y, a1.z, a1.w};
      float bv[4] = {b.x, b.y, b.z, b.w};
#pragma unroll
      for (int i = 0; i < 8; ++i)
#pragma unroll
        for (int j = 0; j < 4; ++j) acc[i][j] = fmaf(av[i], bv[j], acc[i][j]);
    }
    __syncthreads();
  }
  float cnv[4];
#pragma unroll
  for (int j = 0; j < 4; ++j) {
    int k = k0 + tx * 4 + j;
    cnv[j] = (k < K) ? cnorm[k] : 0.f;
  }
#pragma unroll
  for (int i = 0; i < 8; ++i) {
    u64 key = ~0ULL;
#pragma unroll
    for (int j = 0; j < 4; ++j) {
      int k = k0 + tx * 4 + j;
      if (k < K) {
        float score = fmaf(-2.f, acc[i][j], cnv[j]);
        u64 cand = ((u64)fsort(score) << 32) | (unsigned)k;
        key = key < cand ? key : cand;
      }
    }
#pragma unroll
    for (int mk = 8; mk >= 1; mk >>= 1) {
      u64 other = __shfl_xor(key, mk, 16);
      key = key < other ? key : other;
    }
    if (tx == 0) atomicMin(&best[n0 + ty * 8 + i], key);
  }
}

// ---------------- shared output kernel ----------------
__global__ void out_kernel(const u64* __restrict__ best, int* __restrict__ out, int N) {
  int n = blockIdx.x * blockDim.x + threadIdx.x;
  if (n < N) out[n] = (int)(u32)(best[n] & 0xffffffffu);
}

extern "C" void kernel_launch(void* const* d_in, const int* in_sizes, int n_in,
                              void* d_out, int out_size, void* d_ws, size_t ws_size,
                              hipStream_t stream) {
  const float* X = (const float*)d_in[0];  // [N, D]
  const float* C = (const float*)d_in[1];  // [D, K]
  int* out = (int*)d_out;

  // ws layout: best | amin | cnorm | Xb | Cb | Ct
  const size_t OFF_BEST = 0;
  const size_t OFF_AMIN = 131072;
  const size_t OFF_CN   = 196608;
  const size_t OFF_XB   = 262144;
  const size_t OFF_CB   = OFF_XB + (size_t)N_ROWS * DDIM * 2;     // 25427968
  const size_t OFF_CT   = OFF_CB + (size_t)KPAD * DDIM * 2;       // 41156608
  const size_t REQ_B    = OFF_CT;                                 // no Ct
  const size_t REQ_A    = OFF_CT + (size_t)KPAD * DDIM * 4;       // 72613888

  if (ws_size >= REQ_B) {
    u64* best = (u64*)((char*)d_ws + OFF_BEST);
    u32* amin = (u32*)((char*)d_ws + OFF_AMIN);
    float* cnp = (float*)((char*)d_ws + OFF_CN);
    unsigned short* Xb = (unsigned short*)((char*)d_ws + OFF_XB);
    unsigned short* Cb = (unsigned short*)((char*)d_ws + OFF_CB);
    float* Ct = (ws_size >= REQ_A) ? (float*)((char*)d_ws + OFF_CT) : nullptr;

    hipLaunchKernelGGL(convx_kernel, dim3(N_ROWS * 96 / 256), dim3(256), 0, stream, X, Xb, best);
    hipLaunchKernelGGL(transc_kernel, dim3(KPAD / 32, DDIM / 32), dim3(256), 0, stream, C, Cb, Ct);
    hipLaunchKernelGGL(cnorm2_kernel, dim3(KPAD / 64), dim3(256), 0, stream, C, cnp);
    hipLaunchKernelGGL(seed_kernel, dim3(N_ROWS / 4), dim3(256), 0, stream, X, Cb, cnp, amin);
    hipLaunchKernelGGL(assign_mfma8, dim3((N_ROWS / 128) * (KPAD / 256)), dim3(512), 0, stream,
                       Xb, Cb, X, C, Ct, cnp, amin, best);
    hipLaunchKernelGGL(out_kernel, dim3(64), dim3(256), 0, stream, best, out, N_ROWS);
  } else {
    // fp32 fallback (round-2 passing path)
    u64* best = (u64*)d_ws;
    float* cnorm = (float*)((char*)d_ws + (size_t)N_ROWS * sizeof(u64));
    hipLaunchKernelGGL(init_kernel, dim3(64), dim3(256), 0, stream, best, N_ROWS);
    hipLaunchKernelGGL(cnorm_kernel, dim3((KCOLS + 255) / 256), dim3(256), 0, stream,
                       C, cnorm, DDIM, KCOLS);
    hipLaunchKernelGGL(assign_kernel, dim3((KCOLS + 63) / 64, N_ROWS / 128), dim3(256), 0,
                       stream, X, C, cnorm, best, N_ROWS, DDIM, KCOLS);
    hipLaunchKernelGGL(out_kernel, dim3(64), dim3(256), 0, stream, best, out, N_ROWS);
  }
}